// Round 3
// baseline (46460.391 us; speedup 1.0000x reference)
//
#include <hip/hip_runtime.h>

#define TT 512
#define BB 256
#define DD 128
#define HH 256
#define NPRE 3072
#define NWG 192
#define NTHR 256
#define KSTR 68    // k-major LDS stride (floats): conflict-free b128 reads, 16B-aligned rows
#define ASTR 132   // row-major A stride for K=128 (x) segments
#define EPSF 1e-5f

__device__ __forceinline__ float sigmf(float x) { return 1.f / (1.f + __expf(-x)); }

// Distributed-flag global barrier: no contended RMW.
// Each WG stores epoch e to its own 128B-padded flag; WG0 threads 0..NWG-1
// poll one flag each; WG0 then publishes e to *release; everyone polls release.
__device__ __forceinline__ void gbar(unsigned* flags, unsigned* release,
                                     int wg, int tid, unsigned e) {
  __syncthreads();
  if (tid == 0) {
    __threadfence();
    __hip_atomic_store(&flags[(size_t)wg * 32], e, __ATOMIC_RELEASE, __HIP_MEMORY_SCOPE_AGENT);
  }
  if (wg == 0) {
    if (tid < NWG) {
      while (__hip_atomic_load(&flags[(size_t)tid * 32], __ATOMIC_ACQUIRE, __HIP_MEMORY_SCOPE_AGENT) < e)
        __builtin_amdgcn_s_sleep(1);
    }
    __syncthreads();
    if (tid == 0)
      __hip_atomic_store(release, e, __ATOMIC_RELEASE, __HIP_MEMORY_SCOPE_AGENT);
  }
  if (tid == 0) {
    while (__hip_atomic_load(release, __ATOMIC_ACQUIRE, __HIP_MEMORY_SCOPE_AGENT) < e)
      __builtin_amdgcn_s_sleep(1);
    __threadfence();
  }
  __syncthreads();
}

// Reduce 8 values over the 256-thread block; results broadcast to all threads.
__device__ __forceinline__ void reduce8(float v[8], float red[][8], int tid) {
  #pragma unroll
  for (int i = 0; i < 8; ++i) {
    float x = v[i];
    #pragma unroll
    for (int off = 32; off > 0; off >>= 1) x += __shfl_down(x, off);
    v[i] = x;
  }
  int w = tid >> 6;
  if ((tid & 63) == 0) {
    #pragma unroll
    for (int i = 0; i < 8; ++i) red[w][i] = v[i];
  }
  __syncthreads();
  #pragma unroll
  for (int i = 0; i < 8; ++i) v[i] = red[0][i] + red[1][i] + red[2][i] + red[3][i];
  __syncthreads();
}

// One LN-GRU cell elementwise phase for one (layer, row b). tid = hidden index j.
__device__ __forceinline__ void cellE(
    const float* __restrict__ pr, int o1, int o2, int o3, int o4,
    const float* __restrict__ B1, const float* __restrict__ B2,
    const float* __restrict__ B3, const float* __restrict__ B4,
    float* __restrict__ hT, int b, int t, int sl,
    float* __restrict__ yrow, float* __restrict__ hyrow,
    float red[][8], int tid)
{
  float v1a = pr[o1 + tid]       + B1[tid];
  float v1b = pr[o1 + 256 + tid] + B1[256 + tid];
  float v2a = pr[o2 + tid]       + B2[tid];
  float v2b = pr[o2 + 256 + tid] + B2[256 + tid];
  float v3  = pr[o3 + tid]       + B3[tid];
  float v4  = pr[o4 + tid]       + B4[tid];
  float v[8] = {v1a + v1b, v1a*v1a + v1b*v1b,
                v2a + v2b, v2a*v2a + v2b*v2b,
                v3, v3*v3, v4, v4*v4};
  reduce8(v, red, tid);
  float m1 = v[0]*(1.f/512.f), r1 = rsqrtf(v[1]*(1.f/512.f) - m1*m1 + EPSF);
  float m2 = v[2]*(1.f/512.f), r2 = rsqrtf(v[3]*(1.f/512.f) - m2*m2 + EPSF);
  float m3 = v[4]*(1.f/256.f), r3 = rsqrtf(v[5]*(1.f/256.f) - m3*m3 + EPSF);
  float m4 = v[6]*(1.f/256.f), r4 = rsqrtf(v[7]*(1.f/256.f) - m4*m4 + EPSF);
  float z  = sigmf((v1a - m1)*r1 + (v2a - m2)*r2);
  float rg = sigmf((v1b - m1)*r1 + (v2b - m2)*r2);
  float hh = tanhf((v3 - m3)*r3 + rg*((v4 - m4)*r4));
  float hp = hT[tid*BB + b];
  float hn = (1.f - z)*hp + z*hh;
  hn = (t < sl) ? hn : 0.f;
  hT[tid*BB + b] = hn;
  if (yrow) yrow[tid] = hn;
  if (t == sl - 1) hyrow[tid] = hn;
}

#define FMA16(A0, A1, A2, A3, W) \
  acc[0][0] += (A0)*(W).x; acc[0][1] += (A0)*(W).y; acc[0][2] += (A0)*(W).z; acc[0][3] += (A0)*(W).w; \
  acc[1][0] += (A1)*(W).x; acc[1][1] += (A1)*(W).y; acc[1][2] += (A1)*(W).z; acc[1][3] += (A1)*(W).w; \
  acc[2][0] += (A2)*(W).x; acc[2][1] += (A2)*(W).y; acc[2][2] += (A2)*(W).z; acc[2][3] += (A2)*(W).w; \
  acc[3][0] += (A3)*(W).x; acc[3][1] += (A3)*(W).y; acc[3][2] += (A3)*(W).z; acc[3][3] += (A3)*(W).w;

extern "C" __global__ void __launch_bounds__(NTHR, 1)
gru_persistent(const float* __restrict__ input, const int* __restrict__ seqlens,
               const float* __restrict__ Wi0, const float* __restrict__ bi0,
               const float* __restrict__ Wh0, const float* __restrict__ bh0,
               const float* __restrict__ Ww0, const float* __restrict__ bw0,
               const float* __restrict__ Wu0, const float* __restrict__ bu0,
               const float* __restrict__ Wi1, const float* __restrict__ bi1,
               const float* __restrict__ Wh1, const float* __restrict__ bh1,
               const float* __restrict__ Ww1, const float* __restrict__ bw1,
               const float* __restrict__ Wu1, const float* __restrict__ bu1,
               float* __restrict__ out, float* __restrict__ ws)
{
  __shared__ float Wl[256 * KSTR];   // weights, k-major [K][64], resident all ticks
  __shared__ float Al[256 * KSTR];   // A tile (k-major for h operands, row-major for x)
  __shared__ float red[4][8];

  unsigned* flags   = (unsigned*)ws;            // NWG * 32 uints (128B-padded flags)
  unsigned* release = (unsigned*)ws + NWG*32;   // 1 uint (own cacheline)
  float* h0T = ws + NWG*32 + 32;                // [H][B] transposed hidden, layer 0
  float* h1T = h0T + HH*BB;                     // [H][B] layer 1
  float* pre = h1T + HH*BB;                     // [B][3072] raw pre-activations

  const int tid = threadIdx.x;
  const int wg  = blockIdx.x;
  const int nt  = wg % 48;
  const int bt  = wg / 48;
  const int b0  = bt * 64;

  int seg;
  if      (nt < 8)  seg = 0;
  else if (nt < 16) seg = 1;
  else if (nt < 20) seg = 2;
  else if (nt < 24) seg = 3;
  else if (nt < 32) seg = 4;
  else if (nt < 40) seg = 5;
  else if (nt < 44) seg = 6;
  else              seg = 7;

  int soff, K, Aid; const float* Wp;
  switch (seg) {   // col-range start, K, A-operand (0=x, 1=h0, 2=h1), weight
    case 0: soff = 0;    K = 128; Aid = 0; Wp = Wi0; break;
    case 1: soff = 512;  K = 256; Aid = 1; Wp = Wh0; break;
    case 2: soff = 1024; K = 128; Aid = 0; Wp = Ww0; break;
    case 3: soff = 1280; K = 256; Aid = 1; Wp = Wu0; break;
    case 4: soff = 1536; K = 256; Aid = 1; Wp = Wi1; break; // x1 = h0[s-1]
    case 5: soff = 2048; K = 256; Aid = 2; Wp = Wh1; break;
    case 6: soff = 2560; K = 256; Aid = 1; Wp = Ww1; break; // x1 = h0[s-1]
    default: soff = 2816; K = 256; Aid = 2; Wp = Wu1; break;
  }
  const int c0  = nt * 64;
  const int nl0 = c0 - soff;

  // ---- one-time: stage this WG's weight slice into LDS, k-major ----
  if (K == 256) {
    for (int n = 0; n < 64; ++n)
      Wl[tid*KSTR + n] = Wp[(size_t)(nl0 + n)*256 + tid];
  } else {
    int k = tid & 127, hp2 = tid >> 7;
    for (int n = hp2; n < 64; n += 2)
      Wl[k*KSTR + n] = Wp[(size_t)(nl0 + n)*128 + k];
  }

  const size_t YSZ = (size_t)TT*BB*HH;
  unsigned ep = 0;

  for (int s = 0; s <= TT; ++s) {
    // ================= M phase: pre[b][c] = A . W^T (no bias) =================
    bool doM = !(s == TT && seg < 4);   // layer-0 segments have no tick T (x OOB)
    if (doM) {
      if (Aid == 0) {
        // x operand: row-major [64][128]
        const float* src = input + ((size_t)s*BB + b0)*DD;
        for (int idx = tid; idx < 64*32; idx += NTHR) {
          int r = idx >> 5, k4 = idx & 31;
          *(float4*)&Al[r*ASTR + 4*k4] = *(const float4*)&src[(size_t)r*DD + 4*k4];
        }
      } else {
        // h operand: copy from transposed state, k-major [256][64]
        const float* src = (Aid == 1 ? h0T : h1T) + b0;
        for (int idx = tid; idx < 256*16; idx += NTHR) {
          int k = idx >> 4, c4 = idx & 15;
          *(float4*)&Al[k*KSTR + 4*c4] = *(const float4*)&src[(size_t)k*BB + 4*c4];
        }
      }
      __syncthreads();

      const int bg = tid >> 4;   // 0..15 -> rows 4*bg..+3
      const int ng = tid & 15;   // 0..15 -> cols 4*ng..+3
      float acc[4][4] = {{0.f,0.f,0.f,0.f},{0.f,0.f,0.f,0.f},{0.f,0.f,0.f,0.f},{0.f,0.f,0.f,0.f}};

      if (Aid == 0) {
        for (int k = 0; k < 128; k += 4) {
          float4 a0 = *(const float4*)&Al[(4*bg + 0)*ASTR + k];
          float4 a1 = *(const float4*)&Al[(4*bg + 1)*ASTR + k];
          float4 a2 = *(const float4*)&Al[(4*bg + 2)*ASTR + k];
          float4 a3 = *(const float4*)&Al[(4*bg + 3)*ASTR + k];
          float4 w;
          w = *(const float4*)&Wl[(k+0)*KSTR + 4*ng]; FMA16(a0.x, a1.x, a2.x, a3.x, w);
          w = *(const float4*)&Wl[(k+1)*KSTR + 4*ng]; FMA16(a0.y, a1.y, a2.y, a3.y, w);
          w = *(const float4*)&Wl[(k+2)*KSTR + 4*ng]; FMA16(a0.z, a1.z, a2.z, a3.z, w);
          w = *(const float4*)&Wl[(k+3)*KSTR + 4*ng]; FMA16(a0.w, a1.w, a2.w, a3.w, w);
        }
      } else {
        #pragma unroll 4
        for (int k = 0; k < 256; ++k) {
          float4 a4 = *(const float4*)&Al[k*KSTR + 4*bg];
          float4 w4 = *(const float4*)&Wl[k*KSTR + 4*ng];
          FMA16(a4.x, a4.y, a4.z, a4.w, w4);
        }
      }
      #pragma unroll
      for (int i = 0; i < 4; ++i) {
        float4 o; o.x = acc[i][0]; o.y = acc[i][1]; o.z = acc[i][2]; o.w = acc[i][3];
        *(float4*)&pre[(size_t)(b0 + 4*bg + i)*NPRE + c0 + 4*ng] = o;
      }
    }
    ++ep; gbar(flags, release, wg, tid, ep);

    // ================= E phase: LN + gates + state update =================
    for (int rr = 0; rr < 2; ++rr) {
      int b = wg + rr*NWG;
      if (b >= BB) break;                 // uniform per WG
      int sl = seqlens[b];
      const float* pr = pre + (size_t)b*NPRE;
      if (s < TT) {                       // layer 0 at t = s
        cellE(pr, 0, 512, 1024, 1280, bi0, bh0, bw0, bu0,
              h0T, b, s, sl,
              nullptr,
              out + YSZ + (size_t)b*HH,
              red, tid);
      }
      if (s >= 1) {                       // layer 1 at t = s-1
        int t1 = s - 1;
        cellE(pr, 1536, 2048, 2560, 2816, bi1, bh1, bw1, bu1,
              h1T, b, t1, sl,
              out + ((size_t)t1*BB + b)*HH,
              out + YSZ + (size_t)BB*HH + (size_t)b*HH,
              red, tid);
      }
    }
    ++ep; gbar(flags, release, wg, tid, ep);
  }
}

extern "C" void kernel_launch(void* const* d_in, const int* in_sizes, int n_in,
                              void* d_out, int out_size, void* d_ws, size_t ws_size,
                              hipStream_t stream) {
  const float* input   = (const float*)d_in[0];
  const int*   seqlens = (const int*)d_in[1];
  const float* Wi0 = (const float*)d_in[2];  const float* bi0 = (const float*)d_in[3];
  const float* Wh0 = (const float*)d_in[4];  const float* bh0 = (const float*)d_in[5];
  const float* Ww0 = (const float*)d_in[6];  const float* bw0 = (const float*)d_in[7];
  const float* Wu0 = (const float*)d_in[8];  const float* bu0 = (const float*)d_in[9];
  const float* Wi1 = (const float*)d_in[10]; const float* bi1 = (const float*)d_in[11];
  const float* Wh1 = (const float*)d_in[12]; const float* bh1 = (const float*)d_in[13];
  const float* Ww1 = (const float*)d_in[14]; const float* bw1 = (const float*)d_in[15];
  const float* Wu1 = (const float*)d_in[16]; const float* bu1 = (const float*)d_in[17];
  float* out = (float*)d_out;
  float* ws  = (float*)d_ws;

  // zero flags (NWG*32 uints) + release pad (32 uints) + h0T + h1T
  hipMemsetAsync(d_ws, 0, (size_t)(NWG*32 + 32)*4 + 2*(size_t)HH*BB*4, stream);

  hipLaunchKernelGGL(gru_persistent, dim3(NWG), dim3(NTHR), 0, stream,
                     input, seqlens,
                     Wi0, bi0, Wh0, bh0, Ww0, bw0, Wu0, bu0,
                     Wi1, bi1, Wh1, bh1, Ww1, bw1, Wu1, bu1,
                     out, ws);
}

// Round 4
// 23162.852 us; speedup vs baseline: 2.0058x; 2.0058x over previous
//
#include <hip/hip_runtime.h>

#define TT 512
#define BB 256
#define DD 128
#define HH 256
#define NPRE 3072
#define NWG 192
#define NTHR 256
#define KSTR 68    // k-major LDS stride (floats): conflict-free b128 reads, 16B-aligned rows
#define ASTR 132   // row-major A stride for K=128 (x) segments
#define EPSF 1e-5f

__device__ __forceinline__ float sigmf(float x) { return 1.f / (1.f + __expf(-x)); }

// ---- agent-coherent (Infinity-Cache) access helpers: no L2 flush needed ----
__device__ __forceinline__ float ldaf(const float* p) {
  return __hip_atomic_load((const float*)p, __ATOMIC_RELAXED, __HIP_MEMORY_SCOPE_AGENT);
}
__device__ __forceinline__ void staf(float* p, float v) {
  __hip_atomic_store(p, v, __ATOMIC_RELAXED, __HIP_MEMORY_SCOPE_AGENT);
}
__device__ __forceinline__ float2 lda2(const float* p) {
  unsigned long long u = __hip_atomic_load((const unsigned long long*)p,
                                           __ATOMIC_RELAXED, __HIP_MEMORY_SCOPE_AGENT);
  union { unsigned long long u; float2 f; } c; c.u = u; return c.f;
}
__device__ __forceinline__ void sta2(float* p, float a, float b) {
  union { unsigned long long u; float f[2]; } c; c.f[0] = a; c.f[1] = b;
  __hip_atomic_store((unsigned long long*)p, c.u,
                     __ATOMIC_RELAXED, __HIP_MEMORY_SCOPE_AGENT);
}

// Distributed-flag barrier, relaxed polls (no per-iteration cache invalidate),
// one acquire fence on exit. Data path is agent-coherent atomics, so only
// ordering (release on flag store) is required.
__device__ __forceinline__ void gbar(unsigned* flags, unsigned* release,
                                     int wg, int tid, unsigned e) {
  __syncthreads();
  if (tid == 0)
    __hip_atomic_store(&flags[(size_t)wg * 32], e, __ATOMIC_RELEASE, __HIP_MEMORY_SCOPE_AGENT);
  if (wg == 0) {
    if (tid < NWG) {
      while (__hip_atomic_load(&flags[(size_t)tid * 32], __ATOMIC_RELAXED, __HIP_MEMORY_SCOPE_AGENT) < e)
        __builtin_amdgcn_s_sleep(1);
    }
    __syncthreads();
    if (tid == 0)
      __hip_atomic_store(release, e, __ATOMIC_RELEASE, __HIP_MEMORY_SCOPE_AGENT);
  }
  if (tid == 0) {
    while (__hip_atomic_load(release, __ATOMIC_RELAXED, __HIP_MEMORY_SCOPE_AGENT) < e)
      __builtin_amdgcn_s_sleep(1);
    __builtin_amdgcn_fence(__ATOMIC_ACQUIRE, "agent");
  }
  __syncthreads();
}

// Reduce 8 values over the 256-thread block; results broadcast to all threads.
__device__ __forceinline__ void reduce8(float v[8], float red[][8], int tid) {
  #pragma unroll
  for (int i = 0; i < 8; ++i) {
    float x = v[i];
    #pragma unroll
    for (int off = 32; off > 0; off >>= 1) x += __shfl_down(x, off);
    v[i] = x;
  }
  int w = tid >> 6;
  if ((tid & 63) == 0) {
    #pragma unroll
    for (int i = 0; i < 8; ++i) red[w][i] = v[i];
  }
  __syncthreads();
  #pragma unroll
  for (int i = 0; i < 8; ++i) v[i] = red[0][i] + red[1][i] + red[2][i] + red[3][i];
  __syncthreads();
}

// One LN-GRU cell elementwise phase for one (layer, row b). tid = hidden index j.
__device__ __forceinline__ void cellE(
    const float* __restrict__ pr, int o1, int o2, int o3, int o4,
    const float* __restrict__ B1, const float* __restrict__ B2,
    const float* __restrict__ B3, const float* __restrict__ B4,
    float* __restrict__ hT, int b, int t, int sl,
    float* __restrict__ yrow, float* __restrict__ hyrow,
    float red[][8], int tid)
{
  float v1a = ldaf(&pr[o1 + tid])       + B1[tid];
  float v1b = ldaf(&pr[o1 + 256 + tid]) + B1[256 + tid];
  float v2a = ldaf(&pr[o2 + tid])       + B2[tid];
  float v2b = ldaf(&pr[o2 + 256 + tid]) + B2[256 + tid];
  float v3  = ldaf(&pr[o3 + tid])       + B3[tid];
  float v4  = ldaf(&pr[o4 + tid])       + B4[tid];
  float v[8] = {v1a + v1b, v1a*v1a + v1b*v1b,
                v2a + v2b, v2a*v2a + v2b*v2b,
                v3, v3*v3, v4, v4*v4};
  reduce8(v, red, tid);
  float m1 = v[0]*(1.f/512.f), r1 = rsqrtf(v[1]*(1.f/512.f) - m1*m1 + EPSF);
  float m2 = v[2]*(1.f/512.f), r2 = rsqrtf(v[3]*(1.f/512.f) - m2*m2 + EPSF);
  float m3 = v[4]*(1.f/256.f), r3 = rsqrtf(v[5]*(1.f/256.f) - m3*m3 + EPSF);
  float m4 = v[6]*(1.f/256.f), r4 = rsqrtf(v[7]*(1.f/256.f) - m4*m4 + EPSF);
  float z  = sigmf((v1a - m1)*r1 + (v2a - m2)*r2);
  float rg = sigmf((v1b - m1)*r1 + (v2b - m2)*r2);
  float hh = tanhf((v3 - m3)*r3 + rg*((v4 - m4)*r4));
  float hp = ldaf(&hT[tid*BB + b]);
  float hn = (1.f - z)*hp + z*hh;
  hn = (t < sl) ? hn : 0.f;
  staf(&hT[tid*BB + b], hn);
  if (yrow) yrow[tid] = hn;
  if (t == sl - 1) hyrow[tid] = hn;
}

#define FMA16(A0, A1, A2, A3, W) \
  acc[0][0] += (A0)*(W).x; acc[0][1] += (A0)*(W).y; acc[0][2] += (A0)*(W).z; acc[0][3] += (A0)*(W).w; \
  acc[1][0] += (A1)*(W).x; acc[1][1] += (A1)*(W).y; acc[1][2] += (A1)*(W).z; acc[1][3] += (A1)*(W).w; \
  acc[2][0] += (A2)*(W).x; acc[2][1] += (A2)*(W).y; acc[2][2] += (A2)*(W).z; acc[2][3] += (A2)*(W).w; \
  acc[3][0] += (A3)*(W).x; acc[3][1] += (A3)*(W).y; acc[3][2] += (A3)*(W).z; acc[3][3] += (A3)*(W).w;

extern "C" __global__ void __launch_bounds__(NTHR, 1)
gru_persistent(const float* __restrict__ input, const int* __restrict__ seqlens,
               const float* __restrict__ Wi0, const float* __restrict__ bi0,
               const float* __restrict__ Wh0, const float* __restrict__ bh0,
               const float* __restrict__ Ww0, const float* __restrict__ bw0,
               const float* __restrict__ Wu0, const float* __restrict__ bu0,
               const float* __restrict__ Wi1, const float* __restrict__ bi1,
               const float* __restrict__ Wh1, const float* __restrict__ bh1,
               const float* __restrict__ Ww1, const float* __restrict__ bw1,
               const float* __restrict__ Wu1, const float* __restrict__ bu1,
               float* __restrict__ out, float* __restrict__ ws)
{
  __shared__ float Wl[256 * KSTR];   // weights, k-major [K][64], resident all ticks
  __shared__ float Al[256 * KSTR];   // A tile (k-major for h operands, row-major for x)
  __shared__ float red[4][8];

  unsigned* flags   = (unsigned*)ws;            // NWG * 32 uints (128B-padded flags)
  unsigned* release = (unsigned*)ws + NWG*32;   // 1 uint (own cacheline)
  float* h0T = ws + NWG*32 + 32;                // [H][B] transposed hidden, layer 0
  float* h1T = h0T + HH*BB;                     // [H][B] layer 1
  float* pre = h1T + HH*BB;                     // [B][3072] raw pre-activations

  const int tid = threadIdx.x;
  const int wg  = blockIdx.x;
  const int nt  = wg % 48;
  const int bt  = wg / 48;
  const int b0  = bt * 64;

  int seg;
  if      (nt < 8)  seg = 0;
  else if (nt < 16) seg = 1;
  else if (nt < 20) seg = 2;
  else if (nt < 24) seg = 3;
  else if (nt < 32) seg = 4;
  else if (nt < 40) seg = 5;
  else if (nt < 44) seg = 6;
  else              seg = 7;

  int soff, K, Aid; const float* Wp;
  switch (seg) {   // col-range start, K, A-operand (0=x, 1=h0, 2=h1), weight
    case 0: soff = 0;    K = 128; Aid = 0; Wp = Wi0; break;
    case 1: soff = 512;  K = 256; Aid = 1; Wp = Wh0; break;
    case 2: soff = 1024; K = 128; Aid = 0; Wp = Ww0; break;
    case 3: soff = 1280; K = 256; Aid = 1; Wp = Wu0; break;
    case 4: soff = 1536; K = 256; Aid = 1; Wp = Wi1; break; // x1 = h0[s-1]
    case 5: soff = 2048; K = 256; Aid = 2; Wp = Wh1; break;
    case 6: soff = 2560; K = 256; Aid = 1; Wp = Ww1; break; // x1 = h0[s-1]
    default: soff = 2816; K = 256; Aid = 2; Wp = Wu1; break;
  }
  const int c0  = nt * 64;
  const int nl0 = c0 - soff;

  // ---- one-time: stage this WG's weight slice into LDS, k-major ----
  if (K == 256) {
    for (int n = 0; n < 64; ++n)
      Wl[tid*KSTR + n] = Wp[(size_t)(nl0 + n)*256 + tid];
  } else {
    int k = tid & 127, hp2 = tid >> 7;
    for (int n = hp2; n < 64; n += 2)
      Wl[k*KSTR + n] = Wp[(size_t)(nl0 + n)*128 + k];
  }

  const size_t YSZ = (size_t)TT*BB*HH;
  unsigned ep = 0;

  for (int s = 0; s <= TT; ++s) {
    // ================= M phase: pre[b][c] = A . W^T (no bias) =================
    bool doM = !(s == TT && seg < 4);   // layer-0 segments have no tick T (x OOB)
    if (doM) {
      if (Aid == 0) {
        // x operand: row-major [64][128] (read-only input: plain cached loads)
        const float* src = input + ((size_t)s*BB + b0)*DD;
        for (int idx = tid; idx < 64*32; idx += NTHR) {
          int r = idx >> 5, k4 = idx & 31;
          *(float4*)&Al[r*ASTR + 4*k4] = *(const float4*)&src[(size_t)r*DD + 4*k4];
        }
      } else {
        // h operand: agent-coherent 8B loads from transposed state, k-major [256][64]
        const float* src = (Aid == 1 ? h0T : h1T) + b0;
        for (int idx = tid; idx < 256*32; idx += NTHR) {
          int k = idx >> 5, c2 = idx & 31;
          float2 v = lda2(&src[(size_t)k*BB + 2*c2]);
          *(float2*)&Al[k*KSTR + 2*c2] = v;
        }
      }
      __syncthreads();

      const int bg = tid >> 4;   // 0..15 -> rows 4*bg..+3
      const int ng = tid & 15;   // 0..15 -> cols 4*ng..+3
      float acc[4][4] = {{0.f,0.f,0.f,0.f},{0.f,0.f,0.f,0.f},{0.f,0.f,0.f,0.f},{0.f,0.f,0.f,0.f}};

      if (Aid == 0) {
        for (int k = 0; k < 128; k += 4) {
          float4 a0 = *(const float4*)&Al[(4*bg + 0)*ASTR + k];
          float4 a1 = *(const float4*)&Al[(4*bg + 1)*ASTR + k];
          float4 a2 = *(const float4*)&Al[(4*bg + 2)*ASTR + k];
          float4 a3 = *(const float4*)&Al[(4*bg + 3)*ASTR + k];
          float4 w;
          w = *(const float4*)&Wl[(k+0)*KSTR + 4*ng]; FMA16(a0.x, a1.x, a2.x, a3.x, w);
          w = *(const float4*)&Wl[(k+1)*KSTR + 4*ng]; FMA16(a0.y, a1.y, a2.y, a3.y, w);
          w = *(const float4*)&Wl[(k+2)*KSTR + 4*ng]; FMA16(a0.z, a1.z, a2.z, a3.z, w);
          w = *(const float4*)&Wl[(k+3)*KSTR + 4*ng]; FMA16(a0.w, a1.w, a2.w, a3.w, w);
        }
      } else {
        #pragma unroll 4
        for (int k = 0; k < 256; ++k) {
          float4 a4 = *(const float4*)&Al[k*KSTR + 4*bg];
          float4 w4 = *(const float4*)&Wl[k*KSTR + 4*ng];
          FMA16(a4.x, a4.y, a4.z, a4.w, w4);
        }
      }
      #pragma unroll
      for (int i = 0; i < 4; ++i) {
        float* dst = &pre[(size_t)(b0 + 4*bg + i)*NPRE + c0 + 4*ng];
        sta2(dst,     acc[i][0], acc[i][1]);
        sta2(dst + 2, acc[i][2], acc[i][3]);
      }
    }
    ++ep; gbar(flags, release, wg, tid, ep);

    // ================= E phase: LN + gates + state update =================
    for (int rr = 0; rr < 2; ++rr) {
      int b = wg + rr*NWG;
      if (b >= BB) break;                 // uniform per WG
      int sl = seqlens[b];
      const float* pr = pre + (size_t)b*NPRE;
      if (s < TT) {                       // layer 0 at t = s
        cellE(pr, 0, 512, 1024, 1280, bi0, bh0, bw0, bu0,
              h0T, b, s, sl,
              nullptr,
              out + YSZ + (size_t)b*HH,
              red, tid);
      }
      if (s >= 1) {                       // layer 1 at t = s-1
        int t1 = s - 1;
        cellE(pr, 1536, 2048, 2560, 2816, bi1, bh1, bw1, bu1,
              h1T, b, t1, sl,
              out + ((size_t)t1*BB + b)*HH,
              out + YSZ + (size_t)BB*HH + (size_t)b*HH,
              red, tid);
      }
    }
    ++ep; gbar(flags, release, wg, tid, ep);
  }
}

extern "C" void kernel_launch(void* const* d_in, const int* in_sizes, int n_in,
                              void* d_out, int out_size, void* d_ws, size_t ws_size,
                              hipStream_t stream) {
  const float* input   = (const float*)d_in[0];
  const int*   seqlens = (const int*)d_in[1];
  const float* Wi0 = (const float*)d_in[2];  const float* bi0 = (const float*)d_in[3];
  const float* Wh0 = (const float*)d_in[4];  const float* bh0 = (const float*)d_in[5];
  const float* Ww0 = (const float*)d_in[6];  const float* bw0 = (const float*)d_in[7];
  const float* Wu0 = (const float*)d_in[8];  const float* bu0 = (const float*)d_in[9];
  const float* Wi1 = (const float*)d_in[10]; const float* bi1 = (const float*)d_in[11];
  const float* Wh1 = (const float*)d_in[12]; const float* bh1 = (const float*)d_in[13];
  const float* Ww1 = (const float*)d_in[14]; const float* bw1 = (const float*)d_in[15];
  const float* Wu1 = (const float*)d_in[16]; const float* bu1 = (const float*)d_in[17];
  float* out = (float*)d_out;
  float* ws  = (float*)d_ws;

  // zero flags (NWG*32 uints) + release pad (32 uints) + h0T + h1T
  hipMemsetAsync(d_ws, 0, (size_t)(NWG*32 + 32)*4 + 2*(size_t)HH*BB*4, stream);

  hipLaunchKernelGGL(gru_persistent, dim3(NWG), dim3(NTHR), 0, stream,
                     input, seqlens,
                     Wi0, bi0, Wh0, bh0, Ww0, bw0, Wu0, bu0,
                     Wi1, bi1, Wh1, bh1, Ww1, bw1, Wu1, bu1,
                     out, ws);
}